// Round 2
// baseline (92.191 us; speedup 1.0000x reference)
//
#include <hip/hip_runtime.h>

// Problem dims
#define BN 8
#define BC 128
#define BH 56
#define BW 56
#define HW 3136
#define NTAP 35
// u16 offsets inside ws:
#define WS_WC 71680                   // stage-2 Wc fragments [WS_WC, WS_WC+4096)
#define WS_XP (WS_WC + 4096)          // padded bf16 im2row x
#define XROW 2368                     // u16 per padded row = 74 cols * 32 ch

typedef unsigned short u16;
typedef unsigned int u32;
typedef __bf16 bf16x8 __attribute__((ext_vector_type(8)));
typedef float f32x4 __attribute__((ext_vector_type(4)));

__device__ __forceinline__ u16 f2b(float f) {
    unsigned u = __float_as_uint(f);
    return (u16)((u + 0x7FFFu + ((u >> 16) & 1u)) >> 16);  // RNE
}
__device__ __forceinline__ u32 pack2(float a, float b) {
    return (u32)f2b(a) | ((u32)f2b(b) << 16);
}
__device__ __forceinline__ void dma16(const void* g, void* l) {
    __builtin_amdgcn_global_load_lds(
        (const __attribute__((address_space(1))) u32*)g,
        (__attribute__((address_space(3))) u32*)l, 16, 0, 0);
}

// prep_all: blocks [0,2048) build padded bf16 im2row x; blocks [2048,2344)
// build frag-ordered w3 + folded Wc (= w5@w4, K zero-padded to 32).
// UNCHANGED (near its ~6 us traffic floor).
__global__ __launch_bounds__(256) void prep_all(
    const float* __restrict__ x, const float* __restrict__ w3,
    const float* __restrict__ w4, const float* __restrict__ w5,
    u16* __restrict__ ws)
{
    const int b = blockIdx.x;
    const int tid = threadIdx.x;

    if (b >= 2048) {               // ---- weights part
        int i = (b - 2048) * 256 + tid;
        if (i < WS_WC) {
            int j = i & 7, lane = (i >> 3) & 63, r = i >> 9;   // r = cc*35+tap
            int tap = r % NTAP, cc = r / NTAP;
            int q = lane >> 4, lm = lane & 15;
            ws[i] = f2b(w3[(lm * BC + cc * 32 + q * 8 + j) * NTAP + tap]);
        } else if (i < WS_WC + 4096) {
            int i2 = i - WS_WC;
            int j = i2 & 7, lane = (i2 >> 3) & 63, ot = i2 >> 9;
            int q = lane >> 4, lm = lane & 15, o = ot * 16 + lm, k = q * 8 + j;
            float s = 0.f;
            if (k < 16)
                for (int c = 0; c < 16; ++c) s += w5[o * 16 + c] * w4[c * 16 + k];
            ws[i] = f2b(s);
        }
        return;
    }

    // ---- x part: xpad[n][cc][hp][col][c32] bf16, h/w zero-pad baked in.
    __shared__ float ls[32][57];
    const int hp = b & 63, cc = (b >> 6) & 3, n = b >> 8;
    u32* dst = (u32*)(ws + WS_XP + (size_t)((n * 4 + cc) * 64 + hp) * XROW);
    const int gr = hp - 4;

    if ((unsigned)gr >= BH) {
        for (int i = tid; i < XROW / 2; i += 256) dst[i] = 0u;
        return;
    }
    for (int i = tid; i < 32 * 14; i += 256) {
        int c = i / 14, w4i = i % 14;
        float4 v = *(const float4*)(x + ((size_t)(n * BC + cc * 32 + c) * BH + gr) * BW + 4 * w4i);
        ls[c][4 * w4i + 0] = v.x;
        ls[c][4 * w4i + 1] = v.y;
        ls[c][4 * w4i + 2] = v.z;
        ls[c][4 * w4i + 3] = v.w;
    }
    __syncthreads();
    for (int i = tid; i < 74 * 16; i += 256) {
        int col = i >> 4, cp = i & 15;
        int gw = col - 9;
        u32 v = 0u;
        if ((unsigned)gw < BW) v = pack2(ls[2 * cp][gw], ls[2 * cp + 1][gw]);
        dst[col * 16 + cp] = v;
    }
}

// conv_mfma v2 (resubmission; prior round failed at container level, audit
// found no kernel-side fault/hang path — memory-safe, uniform barriers).
// Full-row blocks (n,h): 448 blocks x 512 threads (8 waves).
// Wave wv = (wp = wv>>2 col-pair, g = wv&3 tap-quarter 9/9/9/8). Each wave
// owns TWO 16-col output tiles (A-frag reused, 1.5 KB LDS read / MFMA).
// Double-buffered xs+wA (128 KB LDS, 1 block/CU): STAGE(cc+1) issued BEFORE
// computing cc, ONE __syncthreads per round (T3-minimum schedule) -- the
// barrier's vmcnt(0) drain waits on loads issued ~18 MFMAs earlier.
// LDS layout (bytes):
#define XSBUF 25600                   // xs[5][80][32] u16 (cols >=74 garbage, unread by valid lanes)
#define WABUF 35840                   // wA[35][64][8] u16
#define XS_OFF 0                      // 2 bufs: [0, 51200)
#define WA_OFF 51200                  // 2 bufs: [51200, 122880)
#define Y3_OFF 122880                 // y3T[64][40] u16 = 5120
#define SMEM_SZ 128000                // 1 block/CU (160 KiB LDS cap)

__global__ __launch_bounds__(512, 2) void conv_mfma(
    const u16* __restrict__ wsT, float* __restrict__ out)
{
    __shared__ __align__(16) char smem[SMEM_SZ];
    u16* y3T = (u16*)(smem + Y3_OFF);
    float* cbuf = (float*)(smem + XS_OFF);  // [2wp][3g'][2tile][64][4] f32, aliases xs buf0

    const int n = blockIdx.x & 7;
    const int h = blockIdx.x >> 3;       // 0..55
    const int tid = threadIdx.x, lane = tid & 63, wv = tid >> 6;
    const int g = wv & 3, wp = wv >> 2;
    const int q = lane >> 4, lm = lane & 15;
    const int c0 = wp * 32 + lm;         // tile-0 col (always < 48)
    const int c1 = c0 + 16;              // tile-1 col (invalid when >= 56)
    const int t0 = 9 * g;
    const int ntap = (g == 3) ? 8 : 9;   // wave-uniform

    // 60 DMA chunks of 1 KB per round: 25 xs (5 rows x 5; 384 B row-tail
    // overrun reads garbage into cols 74..79 — stays ~9.4 MB inside the
    // ~268 MB ws, consumed only by masked lanes) + 35 wA.
#define STAGE(CC, BUF) do {                                                   \
        const u16* xbase = wsT + WS_XP + (size_t)((n * 4 + (CC)) * 64 + h) * XROW; \
        const u16* wbase = wsT + (size_t)(CC) * NTAP * 512;                   \
        char* xd = smem + XS_OFF + (BUF) * XSBUF;                             \
        char* wd = smem + WA_OFF + (BUF) * WABUF;                             \
        for (int k = wv; k < 60; k += 8) {                                    \
            if (k < 25) {                                                     \
                int r = k / 5, s = k - 5 * r;                                 \
                dma16(xbase + (size_t)(2 * r) * XROW + s * 512 + lane * 8,    \
                      xd + r * 5120 + s * 1024 + lane * 16);                  \
            } else {                                                          \
                int k2 = k - 25;                                              \
                dma16(wbase + (size_t)k2 * 512 + lane * 8,                    \
                      wd + (size_t)k2 * 1024 + lane * 16);                    \
            }                                                                 \
        }                                                                     \
    } while (0)

    f32x4 acc0 = {0.f, 0.f, 0.f, 0.f};
    f32x4 acc1 = {0.f, 0.f, 0.f, 0.f};

    STAGE(0, 0);
    // y3T K-pad zero: all 64 rows, u32 cols 8..15 (u16 16..31), one per thread
    ((u32*)(y3T + (tid >> 3) * 40))[8 + (tid & 7)] = 0u;
    __syncthreads();                     // drains prologue DMA

    #pragma unroll
    for (int cc = 0; cc < 4; ++cc) {
        const int buf = cc & 1;
        if (cc < 3) STAGE(cc + 1, buf ^ 1);   // issue next round's loads FIRST
        const u16* xsb = (const u16*)(smem + XS_OFF + buf * XSBUF);
        const u16* wAb = (const u16*)(smem + WA_OFF + buf * WABUF);
        #pragma unroll
        for (int tt = 0; tt < 9; ++tt) {
            if (tt < ntap) {                  // wave-uniform
                const int t = t0 + tt;
                const int kh = t / 7, kw = t - 7 * kh;
                bf16x8 a = *(const bf16x8*)(wAb + (size_t)(t * 64 + lane) * 8);
                const u16* xrow = xsb + (size_t)(kh * 80 + 3 * kw) * 32 + q * 8;
                bf16x8 b0 = *(const bf16x8*)(xrow + (size_t)c0 * 32);
                acc0 = __builtin_amdgcn_mfma_f32_16x16x32_bf16(a, b0, acc0, 0, 0, 0);
                bf16x8 b1 = *(const bf16x8*)(xrow + (size_t)c1 * 32);
                acc1 = __builtin_amdgcn_mfma_f32_16x16x32_bf16(a, b1, acc1, 0, 0, 0);
            }
        }
        if (cc < 3) __syncthreads();          // drains STAGE(cc+1), fences WAR
    }

    // K-combine over tap-quarters. cbuf aliases xs buf0: last buf0 reads were
    // round cc=2, fenced by that round's sync; round 3 reads buf1 only.
    if (g > 0) {
        float* cb = cbuf + (size_t)(((wp * 3 + (g - 1)) * 2) * 64 + lane) * 4;
        *(f32x4*)cb = acc0;
        *(f32x4*)(cb + 256) = acc1;          // +64*4 floats = tile 1
    }
    __syncthreads();
    if (g == 0) {
        #pragma unroll
        for (int p = 0; p < 3; ++p) {
            const float* cb = cbuf + (size_t)(((wp * 3 + p) * 2) * 64 + lane) * 4;
            f32x4 v0 = *(const f32x4*)cb;
            f32x4 v1 = *(const f32x4*)(cb + 256);
            acc0[0] += v0[0]; acc0[1] += v0[1]; acc0[2] += v0[2]; acc0[3] += v0[3];
            acc1[0] += v1[0]; acc1[1] += v1[1]; acc1[2] += v1[2]; acc1[3] += v1[3];
        }
        const bool ok1 = (c1 < BW);          // c0 always valid
        *(u32*)(y3T + c0 * 40 + q * 4)     = pack2(acc0[0], acc0[1]);
        *(u32*)(y3T + c0 * 40 + q * 4 + 2) = pack2(acc0[2], acc0[3]);
        *(u32*)(y3T + c1 * 40 + q * 4)     = ok1 ? pack2(acc1[0], acc1[1]) : 0u;
        *(u32*)(y3T + c1 * 40 + q * 4 + 2) = ok1 ? pack2(acc1[2], acc1[3]) : 0u;
    }
    __syncthreads();

    // Stage-2: wave wv -> col-tile ct = wv&3, o-tiles {4*(wv>>2) .. +3}.
    const int ct = wv & 3, og = wv >> 2;
    const int wgc = ct * 16 + lm;
    bf16x8 bfrag = *(const bf16x8*)(y3T + (size_t)wgc * 40 + q * 8);
    #pragma unroll
    for (int i = 0; i < 4; ++i) {
        const int ot = 4 * og + i;
        bf16x8 afrag = *(const bf16x8*)(wsT + WS_WC + (size_t)(ot * 64 + lane) * 8);
        f32x4 c2 = {0.f, 0.f, 0.f, 0.f};
        c2 = __builtin_amdgcn_mfma_f32_16x16x32_bf16(afrag, bfrag, c2, 0, 0, 0);
        if (wgc < BW) {
            const int o = ot * 16 + q * 4;
            float* po = out + ((size_t)(n * BC + o) * BH + h) * BW + wgc;
            po[0]      = c2[0];
            po[HW]     = c2[1];
            po[2 * HW] = c2[2];
            po[3 * HW] = c2[3];
        }
    }
#undef STAGE
}

extern "C" void kernel_launch(void* const* d_in, const int* in_sizes, int n_in,
                              void* d_out, int out_size, void* d_ws, size_t ws_size,
                              hipStream_t stream)
{
    (void)in_sizes; (void)n_in; (void)out_size; (void)ws_size;
    const float* x  = (const float*)d_in[0];
    const float* w3 = (const float*)d_in[1];
    const float* w4 = (const float*)d_in[2];
    const float* w5 = (const float*)d_in[3];
    u16* ws = (u16*)d_ws;

    prep_all<<<2048 + 296, 256, 0, stream>>>(x, w3, w4, w5, ws);
    conv_mfma<<<BN * BH, 512, 0, stream>>>(ws, (float*)d_out);
}

// Round 3
// 88.011 us; speedup vs baseline: 1.0475x; 1.0475x over previous
//
#include <hip/hip_runtime.h>

// Problem dims
#define BN 8
#define BC 128
#define BH 56
#define BW 56
#define HW 3136
#define NTAP 35
// u16 offsets inside ws:
#define WS_WC 71680                   // stage-2 Wc fragments [WS_WC, WS_WC+4096)
#define WS_XP (WS_WC + 4096)          // padded bf16 im2row x
#define XROW 2368                     // u16 per padded row = 74 cols * 32 ch

typedef unsigned short u16;
typedef unsigned int u32;
typedef __bf16 bf16x8 __attribute__((ext_vector_type(8)));
typedef float f32x4 __attribute__((ext_vector_type(4)));

__device__ __forceinline__ u16 f2b(float f) {
    unsigned u = __float_as_uint(f);
    return (u16)((u + 0x7FFFu + ((u >> 16) & 1u)) >> 16);  // RNE
}
__device__ __forceinline__ u32 pack2(float a, float b) {
    return (u32)f2b(a) | ((u32)f2b(b) << 16);
}
__device__ __forceinline__ void dma16(const void* g, void* l) {
    __builtin_amdgcn_global_load_lds(
        (const __attribute__((address_space(1))) u32*)g,
        (__attribute__((address_space(3))) u32*)l, 16, 0, 0);
}

// prep_all: blocks [0,2048) build padded bf16 im2row x; blocks [2048,2344)
// build frag-ordered w3 + folded Wc (= w5@w4, K zero-padded to 32).
// UNCHANGED (near its ~6 us traffic floor).
__global__ __launch_bounds__(256) void prep_all(
    const float* __restrict__ x, const float* __restrict__ w3,
    const float* __restrict__ w4, const float* __restrict__ w5,
    u16* __restrict__ ws)
{
    const int b = blockIdx.x;
    const int tid = threadIdx.x;

    if (b >= 2048) {               // ---- weights part
        int i = (b - 2048) * 256 + tid;
        if (i < WS_WC) {
            int j = i & 7, lane = (i >> 3) & 63, r = i >> 9;   // r = cc*35+tap
            int tap = r % NTAP, cc = r / NTAP;
            int q = lane >> 4, lm = lane & 15;
            ws[i] = f2b(w3[(lm * BC + cc * 32 + q * 8 + j) * NTAP + tap]);
        } else if (i < WS_WC + 4096) {
            int i2 = i - WS_WC;
            int j = i2 & 7, lane = (i2 >> 3) & 63, ot = i2 >> 9;
            int q = lane >> 4, lm = lane & 15, o = ot * 16 + lm, k = q * 8 + j;
            float s = 0.f;
            if (k < 16)
                for (int c = 0; c < 16; ++c) s += w5[o * 16 + c] * w4[c * 16 + k];
            ws[i] = f2b(s);
        }
        return;
    }

    // ---- x part: xpad[n][cc][hp][col][c32] bf16, h/w zero-pad baked in.
    __shared__ float ls[32][57];
    const int hp = b & 63, cc = (b >> 6) & 3, n = b >> 8;
    u32* dst = (u32*)(ws + WS_XP + (size_t)((n * 4 + cc) * 64 + hp) * XROW);
    const int gr = hp - 4;

    if ((unsigned)gr >= BH) {
        for (int i = tid; i < XROW / 2; i += 256) dst[i] = 0u;
        return;
    }
    for (int i = tid; i < 32 * 14; i += 256) {
        int c = i / 14, w4i = i % 14;
        float4 v = *(const float4*)(x + ((size_t)(n * BC + cc * 32 + c) * BH + gr) * BW + 4 * w4i);
        ls[c][4 * w4i + 0] = v.x;
        ls[c][4 * w4i + 1] = v.y;
        ls[c][4 * w4i + 2] = v.z;
        ls[c][4 * w4i + 3] = v.w;
    }
    __syncthreads();
    for (int i = tid; i < 74 * 16; i += 256) {
        int col = i >> 4, cp = i & 15;
        int gw = col - 9;
        u32 v = 0u;
        if ((unsigned)gw < BW) v = pack2(ls[2 * cp][gw], ls[2 * cp + 1][gw]);
        dst[col * 16 + cp] = v;
    }
}

// conv_mfma v3: v2's schedule + occupancy restored.
//  * wA LDS ELIMINATED: A-frags are register-loaded straight from global
//    (143 KB of weights, identical for all 448 blocks -> L2-broadcast).
//    A-loads are issued BEFORE the STAGE DMAs so MFMA vmcnt waits never
//    cover next-tile staging.
//  * LDS = xs dbuf (2x25.6 KB) + y3T (5 KB) = 56.3 KB -> 2 blocks/CU,
//    all 448 blocks co-resident (224 CUs x 2), sibling block hides barriers.
//  * __launch_bounds__(512,4): 4 waves/SIMD (16/CU), VGPR cap 128.
// Wave wv = (wp = wv>>2 col-pair, g = wv&3 tap-quarter 9/9/9/8); each wave
// owns two 16-col tiles (A-frag reused across both MFMAs).
// LDS layout (bytes):
#define XSBUF 25600                   // xs[5][80][32] u16 (cols >=74 garbage, masked lanes only)
#define XS_OFF 0                      // 2 bufs: [0, 51200)
#define Y3_OFF 51200                  // y3T[64][40] u16 = 5120
#define SMEM_SZ 56320                 // 2 blocks/CU (160 KiB cap)

__global__ __launch_bounds__(512, 4) void conv_mfma(
    const u16* __restrict__ wsT, float* __restrict__ out)
{
    __shared__ __align__(16) char smem[SMEM_SZ];
    u16* y3T = (u16*)(smem + Y3_OFF);
    float* cbuf = (float*)(smem + XS_OFF);  // [2wp][3g'][2tile][64][4] f32, aliases xs buf0

    const int n = blockIdx.x & 7;        // = XCD under round-robin dispatch: per-n xpad slice (1.2 MB) stays in one L2
    const int h = blockIdx.x >> 3;       // 0..55
    const int tid = threadIdx.x, lane = tid & 63, wv = tid >> 6;
    const int g = wv & 3, wp = wv >> 2;
    const int q = lane >> 4, lm = lane & 15;
    const int c0 = wp * 32 + lm;         // tile-0 col (always < 48)
    const int c1 = c0 + 16;              // tile-1 col (invalid when >= 56)
    const int t0 = 9 * g;
    const int ntap = (g == 3) ? 8 : 9;   // wave-uniform

    // xs staging: 25 DMA chunks of 1 KB per round (5 rows x 5 chunks; 384 B
    // row-tail overrun reads garbage into cols 74..79, consumed only by
    // masked lanes; stays ~9.4 MB inside the 256 MiB ws).
#define STAGE(CC, BUF) do {                                                   \
        const u16* xbase = wsT + WS_XP + (size_t)((n * 4 + (CC)) * 64 + h) * XROW; \
        char* xd = smem + XS_OFF + (BUF) * XSBUF;                             \
        for (int k = wv; k < 25; k += 8) {                                    \
            int r = k / 5, s = k - 5 * r;                                     \
            dma16(xbase + (size_t)(2 * r) * XROW + s * 512 + lane * 8,        \
                  xd + r * 5120 + s * 1024 + lane * 16);                      \
        }                                                                     \
    } while (0)

    f32x4 acc0 = {0.f, 0.f, 0.f, 0.f};
    f32x4 acc1 = {0.f, 0.f, 0.f, 0.f};

    STAGE(0, 0);
    // y3T K-pad zero: all 64 rows, u32 cols 8..15 (u16 16..31), one per thread
    ((u32*)(y3T + (tid >> 3) * 40))[8 + (tid & 7)] = 0u;
    __syncthreads();                     // drains prologue DMA

    #pragma unroll
    for (int cc = 0; cc < 4; ++cc) {
        const int buf = cc & 1;
        // A-frags for this round: register loads from global (L2-resident
        // broadcast), issued FIRST so their vmcnt waits exclude the DMAs.
        bf16x8 a[9];
        #pragma unroll
        for (int tt = 0; tt < 9; ++tt) {
            if (tt < ntap)               // wave-uniform
                a[tt] = *(const bf16x8*)(wsT + (size_t)(cc * NTAP + t0 + tt) * 512 + lane * 8);
        }
        if (cc < 3) STAGE(cc + 1, buf ^ 1);   // next round's loads in flight across the barrier
        const u16* xsb = (const u16*)(smem + XS_OFF + buf * XSBUF);
        #pragma unroll
        for (int tt = 0; tt < 9; ++tt) {
            if (tt < ntap) {                  // wave-uniform
                const int t = t0 + tt;
                const int kh = t / 7, kw = t - 7 * kh;
                const u16* xrow = xsb + (size_t)(kh * 80 + 3 * kw) * 32 + q * 8;
                bf16x8 b0 = *(const bf16x8*)(xrow + (size_t)c0 * 32);
                acc0 = __builtin_amdgcn_mfma_f32_16x16x32_bf16(a[tt], b0, acc0, 0, 0, 0);
                bf16x8 b1 = *(const bf16x8*)(xrow + (size_t)c1 * 32);
                acc1 = __builtin_amdgcn_mfma_f32_16x16x32_bf16(a[tt], b1, acc1, 0, 0, 0);
            }
        }
        if (cc < 3) __syncthreads();          // drains STAGE(cc+1), fences WAR
    }

    // K-combine over tap-quarters. cbuf aliases xs buf0: last buf0 reads were
    // round cc=2, fenced by that round's sync; round 3 reads buf1 only.
    if (g > 0) {
        float* cb = cbuf + (size_t)(((wp * 3 + (g - 1)) * 2) * 64 + lane) * 4;
        *(f32x4*)cb = acc0;
        *(f32x4*)(cb + 256) = acc1;          // +64*4 floats = tile 1
    }
    __syncthreads();
    if (g == 0) {
        #pragma unroll
        for (int p = 0; p < 3; ++p) {
            const float* cb = cbuf + (size_t)(((wp * 3 + p) * 2) * 64 + lane) * 4;
            f32x4 v0 = *(const f32x4*)cb;
            f32x4 v1 = *(const f32x4*)(cb + 256);
            acc0[0] += v0[0]; acc0[1] += v0[1]; acc0[2] += v0[2]; acc0[3] += v0[3];
            acc1[0] += v1[0]; acc1[1] += v1[1]; acc1[2] += v1[2]; acc1[3] += v1[3];
        }
        const bool ok1 = (c1 < BW);          // c0 always valid
        *(u32*)(y3T + c0 * 40 + q * 4)     = pack2(acc0[0], acc0[1]);
        *(u32*)(y3T + c0 * 40 + q * 4 + 2) = pack2(acc0[2], acc0[3]);
        *(u32*)(y3T + c1 * 40 + q * 4)     = ok1 ? pack2(acc1[0], acc1[1]) : 0u;
        *(u32*)(y3T + c1 * 40 + q * 4 + 2) = ok1 ? pack2(acc1[2], acc1[3]) : 0u;
    }
    __syncthreads();

    // Stage-2: wave wv -> col-tile ct = wv&3, o-tiles {4*(wv>>2) .. +3}.
    const int ct = wv & 3, og = wv >> 2;
    const int wgc = ct * 16 + lm;
    bf16x8 bfrag = *(const bf16x8*)(y3T + (size_t)wgc * 40 + q * 8);
    #pragma unroll
    for (int i = 0; i < 4; ++i) {
        const int ot = 4 * og + i;
        bf16x8 afrag = *(const bf16x8*)(wsT + WS_WC + (size_t)(ot * 64 + lane) * 8);
        f32x4 c2 = {0.f, 0.f, 0.f, 0.f};
        c2 = __builtin_amdgcn_mfma_f32_16x16x32_bf16(afrag, bfrag, c2, 0, 0, 0);
        if (wgc < BW) {
            const int o = ot * 16 + q * 4;
            float* po = out + ((size_t)(n * BC + o) * BH + h) * BW + wgc;
            po[0]      = c2[0];
            po[HW]     = c2[1];
            po[2 * HW] = c2[2];
            po[3 * HW] = c2[3];
        }
    }
#undef STAGE
}

extern "C" void kernel_launch(void* const* d_in, const int* in_sizes, int n_in,
                              void* d_out, int out_size, void* d_ws, size_t ws_size,
                              hipStream_t stream)
{
    (void)in_sizes; (void)n_in; (void)out_size; (void)ws_size;
    const float* x  = (const float*)d_in[0];
    const float* w3 = (const float*)d_in[1];
    const float* w4 = (const float*)d_in[2];
    const float* w5 = (const float*)d_in[3];
    u16* ws = (u16*)d_ws;

    prep_all<<<2048 + 296, 256, 0, stream>>>(x, w3, w4, w5, ws);
    conv_mfma<<<BN * BH, 512, 0, stream>>>(ws, (float*)d_out);
}

// Round 4
// 85.361 us; speedup vs baseline: 1.0800x; 1.0311x over previous
//
#include <hip/hip_runtime.h>

// Problem dims
#define BN 8
#define BC 128
#define BH 56
#define BW 56
#define HW 3136
#define NTAP 35
// u16 offsets inside ws (weights only now):
#define WS_WC 71680                   // stage-2 Wc fragments [WS_WC, WS_WC+4096)

typedef unsigned short u16;
typedef unsigned int u32;
typedef __bf16 bf16x8 __attribute__((ext_vector_type(8)));
typedef float f32x4 __attribute__((ext_vector_type(4)));

__device__ __forceinline__ u16 f2b(float f) {
    unsigned u = __float_as_uint(f);
    return (u16)((u + 0x7FFFu + ((u >> 16) & 1u)) >> 16);  // RNE
}
__device__ __forceinline__ u32 pack2(float a, float b) {
    return (u32)f2b(a) | ((u32)f2b(b) << 16);
}

// prep_w: weights only (x im2row pre-pass eliminated — conv stages from x
// directly). 296 blocks x 256 = 75,776 threads = WS_WC + 4096 exactly.
// Builds frag-ordered w3 (wA) + folded Wc (= w5@w4, K zero-padded to 32).
__global__ __launch_bounds__(256) void prep_w(
    const float* __restrict__ w3, const float* __restrict__ w4,
    const float* __restrict__ w5, u16* __restrict__ ws)
{
    int i = blockIdx.x * 256 + threadIdx.x;
    if (i < WS_WC) {
        int j = i & 7, lane = (i >> 3) & 63, r = i >> 9;   // r = cc*35+tap
        int tap = r % NTAP, cc = r / NTAP;
        int q = lane >> 4, lm = lane & 15;
        ws[i] = f2b(w3[(lm * BC + cc * 32 + q * 8 + j) * NTAP + tap]);
    } else if (i < WS_WC + 4096) {
        int i2 = i - WS_WC;
        int j = i2 & 7, lane = (i2 >> 3) & 63, ot = i2 >> 9;
        int q = lane >> 4, lm = lane & 15, o = ot * 16 + lm, k = q * 8 + j;
        float s = 0.f;
        if (k < 16)
            for (int c = 0; c < 16; ++c) s += w5[o * 16 + c] * w4[c * 16 + k];
        ws[i] = f2b(s);
    }
}

// conv_mfma v4: fused im2row — blocks read x directly (L2-local per XCD:
// n = blockIdx&7 ~ XCD id; each XCD touches only its 1.6 MB x-slice).
// 448 blocks (n,h) x 512 threads (8 waves). Wave wv = (wp=wv>>2 col-pair,
// g=wv&3 tap-quarter 9/9/9/8); each wave owns two 16-col tiles.
// Staging is register-split (T14): SLOAD(cc+1) issued before compute(cc),
// pack2 + ds_write after; one barrier per round. Double-buffered xs.
// xs col stride padded 32->40 u16 (16B-aligned b128; conflict-free reads
// AND writes). Pad cols / invalid rows zeroed ONCE (round-invariant).
// LDS layout (bytes):
#define COLW 40                       // u16 per col (32 data + 8 pad)
#define XSBUF 32000                   // xs[5][80][COLW] u16
#define U32BUF 8000                   // XSBUF/4
#define Y3_OFF 64000                  // y3T[64][40] u16 = 5120
#define SMEM_SZ 69632                 // 69120 + 512 slack (benign masked-lane
                                      // col-overrun reads); 2 blocks/CU

__global__ __launch_bounds__(512, 4) void conv_mfma(
    const float* __restrict__ x, const u16* __restrict__ wsT,
    float* __restrict__ out)
{
    __shared__ __align__(16) char smem[SMEM_SZ];
    u16* y3T = (u16*)(smem + Y3_OFF);
    float* cbuf = (float*)smem;          // aliases xs buf0 in epilogue

    const int n = blockIdx.x & 7;
    const int h = blockIdx.x >> 3;       // 0..55
    const int tid = threadIdx.x, lane = tid & 63, wv = tid >> 6;
    const int g = wv & 3, wp = wv >> 2;
    const int q = lane >> 4, lm = lane & 15;
    const int c0 = wp * 32 + lm;         // tile-0 col (always < 48)
    const int c1 = c0 + 16;              // tile-1 col (invalid when >= 56)
    const int t0 = 9 * g;
    const int ntap = (g == 3) ? 8 : 9;   // wave-uniform

    // ---- staging: 1120 items = 5r x 16cp x 14wq; thread does <=3.
    // item: load x[n][cc*32+2cp(+1)][gr][4wq..+3] (2x float4), pack to 4 u32,
    // write cols 9+4wq..+3 at channel-pair cp. Layout: u32 idx
    // (r*80+col)*20 + cp. Lanes step wq->cp... cp fastest in `rem%14` decode
    // keeps writes 2-way (free) via the 40-u16 col stride.
    float4 sa[3], sb[3];
#define SLOAD(CC) do {                                                        \
        _Pragma("unroll")                                                     \
        for (int u = 0; u < 3; ++u) {                                         \
            int it = tid + u * 512;                                           \
            if (it < 1120) {                                                  \
                int r = it / 224, rem = it % 224;                             \
                int cp = rem / 14, wq = rem % 14;                             \
                int gr = h - 4 + 2 * r;                                       \
                if ((unsigned)gr < BH) {                                      \
                    const float* px = x + ((size_t)(n * BC + (CC) * 32 + 2 * cp) * BH + gr) * BW + 4 * wq; \
                    sa[u] = *(const float4*)px;                               \
                    sb[u] = *(const float4*)(px + HW);                        \
                }                                                             \
            }                                                                 \
        }                                                                     \
    } while (0)

#define SWRITE(BUF) do {                                                      \
        u32* xb = (u32*)(smem + (BUF) * XSBUF);                               \
        _Pragma("unroll")                                                     \
        for (int u = 0; u < 3; ++u) {                                         \
            int it = tid + u * 512;                                           \
            if (it < 1120) {                                                  \
                int r = it / 224, rem = it % 224;                             \
                int cp = rem / 14, wq = rem % 14;                             \
                int gr = h - 4 + 2 * r;                                       \
                if ((unsigned)gr < BH) {                                      \
                    u32* d = xb + (r * 80 + 9 + 4 * wq) * 20 + cp;            \
                    d[0]  = pack2(sa[u].x, sb[u].x);                          \
                    d[20] = pack2(sa[u].y, sb[u].y);                          \
                    d[40] = pack2(sa[u].z, sb[u].z);                          \
                    d[60] = pack2(sa[u].w, sb[u].w);                          \
                }                                                             \
            }                                                                 \
        }                                                                     \
    } while (0)

    // ---- prologue: zeros (round-invariant cells) + round-0 stage.
    // All writes below are mutually disjoint -> no intermediate barrier.
    SLOAD(0);
    // pad cols 0..8, 65..79: 2buf x 5r x 24pc x 16cp = 3840 u32
    for (int i = tid; i < 3840; i += 512) {
        int cp = i & 15, t = i >> 4;
        int pc = t % 24, t2 = t / 24;
        int r = t2 % 5, bb = t2 / 5;
        int col = pc < 9 ? pc : 56 + pc;
        ((u32*)smem)[bb * U32BUF + (r * 80 + col) * 20 + cp] = 0u;
    }
    // invalid rows (<=2, edge blocks only): zero cols 9..64 in both bufs
    int bad0 = 0, bad1 = 0, nb = 0;
    #pragma unroll
    for (int r = 0; r < 5; ++r) {
        int gr = h - 4 + 2 * r;
        if ((unsigned)gr >= BH) { if (nb == 0) bad0 = r; else bad1 = r; ++nb; }
    }
    for (int i = tid; i < nb * 1792; i += 512) {   // 1792 = 2buf*56*16
        int cp = i & 15, t = i >> 4;
        int w = t % 56, t2 = t / 56;
        int bb = t2 & 1, r = (t2 >> 1) ? bad1 : bad0;
        ((u32*)smem)[bb * U32BUF + (r * 80 + 9 + w) * 20 + cp] = 0u;
    }
    // y3T K-pad zero: 64 rows x u32 cols 8..15, one per thread
    ((u32*)(y3T + (tid >> 3) * 40))[8 + (tid & 7)] = 0u;
    SWRITE(0);
    __syncthreads();                     // zeros + round-0 data visible

    f32x4 acc0 = {0.f, 0.f, 0.f, 0.f};
    f32x4 acc1 = {0.f, 0.f, 0.f, 0.f};

    #pragma unroll
    for (int cc = 0; cc < 4; ++cc) {
        const int buf = cc & 1;
        // A-frags (L2-broadcast from ws), issued first
        bf16x8 a[9];
        #pragma unroll
        for (int tt = 0; tt < 9; ++tt) {
            if (tt < ntap)               // wave-uniform
                a[tt] = *(const bf16x8*)(wsT + (size_t)(cc * NTAP + t0 + tt) * 512 + lane * 8);
        }
        if (cc < 3) SLOAD(cc + 1);       // next round's x loads in flight under MFMA
        const u16* xsb = (const u16*)(smem + buf * XSBUF);
        #pragma unroll
        for (int tt = 0; tt < 9; ++tt) {
            if (tt < ntap) {             // wave-uniform
                const int t = t0 + tt;
                const int kh = t / 7, kw = t - 7 * kh;
                const u16* xrow = xsb + (size_t)(kh * 80 + 3 * kw) * COLW + q * 8;
                bf16x8 b0 = *(const bf16x8*)(xrow + (size_t)c0 * COLW);
                acc0 = __builtin_amdgcn_mfma_f32_16x16x32_bf16(a[tt], b0, acc0, 0, 0, 0);
                bf16x8 b1 = *(const bf16x8*)(xrow + (size_t)c1 * COLW);
                acc1 = __builtin_amdgcn_mfma_f32_16x16x32_bf16(a[tt], b1, acc1, 0, 0, 0);
            }
        }
        if (cc < 3) {
            SWRITE(buf ^ 1);             // pack + ds_write cc+1 into other buf
            __syncthreads();             // writes visible; WAR on buf fenced
        }
    }

    // K-combine over tap-quarters. cbuf aliases xs buf0: buf0's last reads
    // were round cc=2 (fenced by its barrier); round 3 reads buf1 only.
    if (g > 0) {
        float* cb = cbuf + (size_t)(((wp * 3 + (g - 1)) * 2) * 64 + lane) * 4;
        *(f32x4*)cb = acc0;
        *(f32x4*)(cb + 256) = acc1;      // +64*4 floats = tile 1
    }
    __syncthreads();
    if (g == 0) {
        #pragma unroll
        for (int p = 0; p < 3; ++p) {
            const float* cb = cbuf + (size_t)(((wp * 3 + p) * 2) * 64 + lane) * 4;
            f32x4 v0 = *(const f32x4*)cb;
            f32x4 v1 = *(const f32x4*)(cb + 256);
            acc0[0] += v0[0]; acc0[1] += v0[1]; acc0[2] += v0[2]; acc0[3] += v0[3];
            acc1[0] += v1[0]; acc1[1] += v1[1]; acc1[2] += v1[2]; acc1[3] += v1[3];
        }
        const bool ok1 = (c1 < BW);      // c0 always valid
        *(u32*)(y3T + c0 * 40 + q * 4)     = pack2(acc0[0], acc0[1]);
        *(u32*)(y3T + c0 * 40 + q * 4 + 2) = pack2(acc0[2], acc0[3]);
        *(u32*)(y3T + c1 * 40 + q * 4)     = ok1 ? pack2(acc1[0], acc1[1]) : 0u;
        *(u32*)(y3T + c1 * 40 + q * 4 + 2) = ok1 ? pack2(acc1[2], acc1[3]) : 0u;
    }
    __syncthreads();

    // Stage-2: wave wv -> col-tile ct = wv&3, o-tiles {4*(wv>>2) .. +3}.
    const int ct = wv & 3, og = wv >> 2;
    const int wgc = ct * 16 + lm;
    bf16x8 bfrag = *(const bf16x8*)(y3T + (size_t)wgc * 40 + q * 8);
    #pragma unroll
    for (int i = 0; i < 4; ++i) {
        const int ot = 4 * og + i;
        bf16x8 afrag = *(const bf16x8*)(wsT + WS_WC + (size_t)(ot * 64 + lane) * 8);
        f32x4 c2 = {0.f, 0.f, 0.f, 0.f};
        c2 = __builtin_amdgcn_mfma_f32_16x16x32_bf16(afrag, bfrag, c2, 0, 0, 0);
        if (wgc < BW) {
            const int o = ot * 16 + q * 4;
            float* po = out + ((size_t)(n * BC + o) * BH + h) * BW + wgc;
            po[0]      = c2[0];
            po[HW]     = c2[1];
            po[2 * HW] = c2[2];
            po[3 * HW] = c2[3];
        }
    }
#undef SLOAD
#undef SWRITE
}

extern "C" void kernel_launch(void* const* d_in, const int* in_sizes, int n_in,
                              void* d_out, int out_size, void* d_ws, size_t ws_size,
                              hipStream_t stream)
{
    (void)in_sizes; (void)n_in; (void)out_size; (void)ws_size;
    const float* x  = (const float*)d_in[0];
    const float* w3 = (const float*)d_in[1];
    const float* w4 = (const float*)d_in[2];
    const float* w5 = (const float*)d_in[3];
    u16* ws = (u16*)d_ws;

    prep_w<<<296, 256, 0, stream>>>(w3, w4, w5, ws);
    conv_mfma<<<BN * BH, 512, 0, stream>>>(x, ws, (float*)d_out);
}